// Round 3
// baseline (2374.402 us; speedup 1.0000x reference)
//
#include <hip/hip_runtime.h>
#include <math.h>

typedef float f4 __attribute__((ext_vector_type(4)));

#define THREADS 256
#define HID 256
#define SMP 16   // samples per block (4 waves x 4 samples)
#define CH 8     // weight k-rows per staged chunk (8x256 fp32 = 8 KB), x2 dbuf

// ---------------- prep: transpose weights into ws ----------------
// ws layout (floats): [0]=W1T 256x256 (W1T[k][n]=W1[n][k]),
//   [65536]=W2T 256x256, [131072]=WoutT 32x256 (WoutT[j][k]=Wout[k][j])
__global__ void k_prep(const float* __restrict__ W1, const float* __restrict__ W2,
                       const float* __restrict__ Wout, float* __restrict__ ws) {
  float* W1T = ws;
  float* W2T = ws + 65536;
  float* WoutT = ws + 131072;
  int tid = blockIdx.x * 256 + threadIdx.x;
  if (tid < 65536) {
    int k = tid >> 8, n = tid & 255;
    W1T[tid] = W1[n * 256 + k];
    W2T[tid] = W2[n * 256 + k];
    if (tid < 8192) {
      int k2 = tid >> 8, n2 = tid & 255;   // WoutT[32][256]
      WoutT[tid] = Wout[n2 * 32 + k2];
    }
  }
}

// softplus = np fp32 semantics (DO NOT TOUCH — mask-critical):
//   sp = max(z,0) + log1pf(expf(-|z|)), each libm call correctly rounded
//   via double intermediates. Verified bit-faithful in rounds 6-8.
__device__ __forceinline__ float sp_cr(float z) {
  float az = fabsf(z);
  float e  = (float)exp(-(double)az);
  float lp = (float)log1p((double)e);
  return fmaxf(z, 0.0f) + lp;
}

// backward factor: sigmoid(z) = 1 - exp(-softplus(z)) from stored activation.
__device__ __forceinline__ float sig_from_h(float h) {
  return 1.0f - __expf(-h);
}

// wave-uniform broadcast of lane ln's value (v_readlane -> SGPR operand)
__device__ __forceinline__ float bcast(float v, int ln) {
  return __uint_as_float(__builtin_amdgcn_readlane(__float_as_uint(v), ln));
}

// async global->LDS DMA, 16B per lane. LDS dest = wave-uniform base + lane*16,
// which matches our linear tid-ordered wbuf layout exactly (lane0 passes base).
__device__ __forceinline__ void gll16(const f4* g, f4* l) {
  __builtin_amdgcn_global_load_lds(
      (const __attribute__((address_space(1))) void*)g,
      (__attribute__((address_space(3))) void*)l, 16, 0, 0);
}

// ---- forward chunk MAC (CH=8): exact np per-element order (ascending k,
// ---- mul-then-add, single accumulator per (s,col)). h via LDS broadcast.
__device__ __forceinline__ void mac_fwd(const float* __restrict__ h0r,
                                        const float* __restrict__ h1r,
                                        const float* __restrict__ h2r,
                                        const float* __restrict__ h3r,
                                        const float* __restrict__ wl,
                                        int l, f4& a0, f4& a1, f4& a2, f4& a3) {
#pragma clang fp contract(off)
  #pragma unroll
  for (int k = 0; k < CH; k += 4) {
    f4 x0 = *(const f4*)&h0r[k];
    f4 x1 = *(const f4*)&h1r[k];
    f4 x2 = *(const f4*)&h2r[k];
    f4 x3 = *(const f4*)&h3r[k];
    #pragma unroll
    for (int kk = 0; kk < 4; ++kk) {
      f4 wv = *(const f4*)&wl[(k + kk) * 256 + l * 4];
      #pragma unroll
      for (int m = 0; m < 4; ++m) { float p = x0[kk] * wv[m]; a0[m] = a0[m] + p; }
      #pragma unroll
      for (int m = 0; m < 4; ++m) { float p = x1[kk] * wv[m]; a1[m] = a1[m] + p; }
      #pragma unroll
      for (int m = 0; m < 4; ++m) { float p = x2[kk] * wv[m]; a2[m] = a2[m] + p; }
      #pragma unroll
      for (int m = 0; m < 4; ++m) { float p = x3[kk] * wv[m]; a3[m] = a3[m] + p; }
    }
  }
}

// ---- backward chunk MAC (CH=8), h via LDS broadcast (used for B2/zm) ----
__device__ __forceinline__ void mac_bwd(const float* __restrict__ h0r,
                                        const float* __restrict__ h1r,
                                        const float* __restrict__ h2r,
                                        const float* __restrict__ h3r,
                                        const float* __restrict__ wl,
                                        int l, f4& a0, f4& a1, f4& a2, f4& a3) {
  #pragma unroll
  for (int k = 0; k < CH; k += 4) {
    f4 x0 = *(const f4*)&h0r[k];
    f4 x1 = *(const f4*)&h1r[k];
    f4 x2 = *(const f4*)&h2r[k];
    f4 x3 = *(const f4*)&h3r[k];
    #pragma unroll
    for (int kk = 0; kk < 4; ++kk) {
      f4 wv = *(const f4*)&wl[(k + kk) * 256 + l * 4];
      #pragma unroll
      for (int m = 0; m < 4; ++m) a0[m] = fmaf(x0[kk], wv[m], a0[m]);
      #pragma unroll
      for (int m = 0; m < 4; ++m) a1[m] = fmaf(x1[kk], wv[m], a1[m]);
      #pragma unroll
      for (int m = 0; m < 4; ++m) a2[m] = fmaf(x2[kk], wv[m], a2[m]);
      #pragma unroll
      for (int m = 0; m < 4; ++m) a3[m] = fmaf(x3[kk], wv[m], a3[m]);
    }
  }
}

// dbuf-staged layer, h from LDS. Per chunk: wait DMA(c); barrier;
// issue DMA(c+1) into other buf; mac(c). One barrier + one vmcnt per chunk;
// DMA latency hides under mac. ds_writes eliminated from the LDS pipe.
template <int K, bool FWD>
__device__ __forceinline__ void layer_lds(const float* __restrict__ Wbase,
                                          const float* __restrict__ hin,
                                          int sA, int l, int tid,
                                          f4 (*wb)[CH * 64],
                                          f4& a0, f4& a1, f4& a2, f4& a3) {
  a0 = (f4){0, 0, 0, 0}; a1 = a0; a2 = a0; a3 = a0;
  constexpr int NC = K / CH;
  __syncthreads();                       // prev users of wb / hin writers done
  {
    const f4* s0 = (const f4*)Wbase;
    gll16(s0 + tid, &wb[0][tid]);
    gll16(s0 + tid + 256, &wb[0][tid + 256]);
  }
  #pragma unroll 1
  for (int c = 0; c < NC; ++c) {
    asm volatile("s_waitcnt vmcnt(0)" ::: "memory");
    __syncthreads();                     // chunk c in LDS; prev readers done
    if (c + 1 < NC) {
      const f4* s2 = (const f4*)(Wbase + (size_t)(c + 1) * CH * 256);
      int nb = (c + 1) & 1;
      gll16(s2 + tid, &wb[nb][tid]);
      gll16(s2 + tid + 256, &wb[nb][tid + 256]);
    }
    const float* wl = (const float*)&wb[c & 1][0];
    const float* h0 = hin + (size_t)(sA + 0) * K + c * CH;
    const float* h1 = hin + (size_t)(sA + 1) * K + c * CH;
    const float* h2 = hin + (size_t)(sA + 2) * K + c * CH;
    const float* h3 = hin + (size_t)(sA + 3) * K + c * CH;
    if constexpr (FWD) mac_fwd(h0, h1, h2, h3, wl, l, a0, a1, a2, a3);
    else               mac_bwd(h0, h1, h2, h3, wl, l, a0, a1, a2, a3);
  }
}

// dbuf-staged bwd layer, dz input carried in the wave's own registers:
// lane l holds dz[s][4l..4l+3], so dz[s][kg] = readlane(d_s[kg&3], kg>>2).
// Removes all h-broadcast LDS reads and the dz store/load entirely.
// Per-accumulator order identical to mac_bwd (ascending kg, fmaf).
template <int K>
__device__ __forceinline__ void layer_reg(const float* __restrict__ Wbase,
                                          f4 d0, f4 d1, f4 d2, f4 d3,
                                          int l, int tid,
                                          f4 (*wb)[CH * 64],
                                          f4& a0, f4& a1, f4& a2, f4& a3) {
  a0 = (f4){0, 0, 0, 0}; a1 = a0; a2 = a0; a3 = a0;
  constexpr int NC = K / CH;
  __syncthreads();
  {
    const f4* s0 = (const f4*)Wbase;
    gll16(s0 + tid, &wb[0][tid]);
    gll16(s0 + tid + 256, &wb[0][tid + 256]);
  }
  #pragma unroll 1
  for (int c = 0; c < NC; ++c) {
    asm volatile("s_waitcnt vmcnt(0)" ::: "memory");
    __syncthreads();
    if (c + 1 < NC) {
      const f4* s2 = (const f4*)(Wbase + (size_t)(c + 1) * CH * 256);
      int nb = (c + 1) & 1;
      gll16(s2 + tid, &wb[nb][tid]);
      gll16(s2 + tid + 256, &wb[nb][tid + 256]);
    }
    const float* wl = (const float*)&wb[c & 1][0];
    #pragma unroll
    for (int kk = 0; kk < CH; ++kk) {
      f4 wv = *(const f4*)&wl[kk * 256 + l * 4];
      int ln = 2 * c + (kk >> 2);        // src lane for kg = c*8+kk
      float b0 = bcast(d0[kk & 3], ln);
      float b1 = bcast(d1[kk & 3], ln);
      float b2 = bcast(d2[kk & 3], ln);
      float b3 = bcast(d3[kk & 3], ln);
      #pragma unroll
      for (int m = 0; m < 4; ++m) a0[m] = fmaf(b0, wv[m], a0[m]);
      #pragma unroll
      for (int m = 0; m < 4; ++m) a1[m] = fmaf(b1, wv[m], a1[m]);
      #pragma unroll
      for (int m = 0; m < 4; ++m) a2[m] = fmaf(b2, wv[m], a2[m]);
      #pragma unroll
      for (int m = 0; m < 4; ++m) a3[m] = fmaf(b3, wv[m], a3[m]);
    }
  }
}

__device__ __forceinline__ void sp_store(f4 a, const float* __restrict__ b,
                                         float* __restrict__ dstrow, int l) {
  f4 bv = *(const f4*)&b[l * 4];
  f4 o;
  #pragma unroll
  for (int m = 0; m < 4; ++m) o[m] = sp_cr(a[m] + bv[m]);
  *(f4*)&dstrow[l * 4] = o;
}

// dz = acc * sig(h) -> returned in registers (no LDS store)
__device__ __forceinline__ f4 sig_ret(f4 a, const float* __restrict__ hrow, int l) {
  f4 h = *(const f4*)&hrow[l * 4];
  f4 d;
  #pragma unroll
  for (int m = 0; m < 4; ++m) d[m] = a[m] * sig_from_h(h[m]);
  return d;
}

// dz0 must land in LDS for BX's (s,j) mapping
__device__ __forceinline__ void sig_store(f4 a, float* __restrict__ hrow, int l) {
  f4 h = *(f4*)&hrow[l * 4];
  #pragma unroll
  for (int m = 0; m < 4; ++m) h[m] = a[m] * sig_from_h(h[m]);
  *(f4*)&hrow[l * 4] = h;
}

// ---------------- fused MLP fwd (np-faithful) + bwd + c = dvdx@G ------------
// R11: (1) global_load_lds DMA staging (ds_writes off the LDS pipe),
// (2) CH=8 double-buffered wbuf — DMA latency hidden under mac, one
// barrier+vmcnt per chunk, (3) backward B1/B0 take dz from registers via
// v_readlane broadcast (no h-broadcast LDS reads, no dz stores). LDS 68 KB,
// 2 blocks/CU preserved (R2's overlap). Summation order bit-identical to R2.
__global__ __launch_bounds__(THREADS, 2) void k_main(
    const float* __restrict__ x,
    const float* __restrict__ W0, const float* __restrict__ b0,
    const float* __restrict__ W1, const float* __restrict__ b1,
    const float* __restrict__ W2, const float* __restrict__ b2,
    const float* __restrict__ Wout, const float* __restrict__ bout,
    const float* __restrict__ G, const float* __restrict__ ws,
    float* __restrict__ out) {
  __shared__ float xs[SMP][32];       // 2 KB
  __shared__ float ha[SMP][HID];      // 16 KB : h0, then dz0
  __shared__ float hb[SMP][HID];      // 16 KB : h1
  __shared__ float hc[SMP][HID];      // 16 KB : h2
  __shared__ float zm[SMP][32];       // 2 KB  : mask, then dvdx
  __shared__ f4 wbuf4[2][CH * 64];    // 16 KB : double-buffered weight chunk

  const float* W1T = ws;
  const float* W2T = ws + 65536;
  const float* WoutT = ws + 131072;

  const int tid = threadIdx.x;
  const int w = tid >> 6;             // wave 0..3 -> samples w*4 .. w*4+3
  const int l = tid & 63;             // cols l*4..l*4+3
  const int sA = w * 4;
  const int s0 = blockIdx.x * SMP;

  for (int i = tid; i < SMP * 32; i += THREADS) {
    xs[i >> 5][i & 31] = x[(size_t)s0 * 32 + i];
  }
  // (layer_lds entry barrier makes xs visible)

  f4 a0, a1, a2, a3;

  // ---- L0: h0 = softplus(xs @ W0 + b0) -> ha  (K=32) ----
  layer_lds<32, true>(W0, &xs[0][0], sA, l, tid, wbuf4, a0, a1, a2, a3);
  sp_store(a0, b0, &ha[sA + 0][0], l);
  sp_store(a1, b0, &ha[sA + 1][0], l);
  sp_store(a2, b0, &ha[sA + 2][0], l);
  sp_store(a3, b0, &ha[sA + 3][0], l);

  // ---- L1: h1 = softplus(h0 @ W1 + b1) -> hb  (K=256) ----
  layer_lds<256, true>(W1, &ha[0][0], sA, l, tid, wbuf4, a0, a1, a2, a3);
  sp_store(a0, b1, &hb[sA + 0][0], l);
  sp_store(a1, b1, &hb[sA + 1][0], l);
  sp_store(a2, b1, &hb[sA + 2][0], l);
  sp_store(a3, b1, &hb[sA + 3][0], l);

  // ---- L2: h2 = softplus(h1 @ W2 + b2) -> hc ----
  layer_lds<256, true>(W2, &hb[0][0], sA, l, tid, wbuf4, a0, a1, a2, a3);
  sp_store(a0, b2, &hc[sA + 0][0], l);
  sp_store(a1, b2, &hc[sA + 1][0], l);
  sp_store(a2, b2, &hc[sA + 2][0], l);
  sp_store(a3, b2, &hc[sA + 3][0], l);
  __syncthreads();                     // hc visible to all threads for L3

  // ---- L3: z3 = h2 @ Wout + bout ; mask -> zm (exact np order; WoutT rows,
  // ---- 32 KB/block, cache-resident — unstaged). 512 (s,j) pairs -> 2 reps. --
  {
#pragma clang fp contract(off)
    #pragma unroll
    for (int rep = 0; rep < 2; ++rep) {
      int idx = tid + rep * THREADS;
      int s = idx >> 5, j = idx & 31;
      const float* wrow = WoutT + (size_t)j * 256;   // WoutT[j][k] = Wout[k][j]
      float acc = 0.0f;
      #pragma unroll 4
      for (int k = 0; k < 256; k += 4) {
        f4 hv = *(const f4*)&hc[s][k];
        f4 wv = *(const f4*)&wrow[k];
        #pragma unroll
        for (int kk = 0; kk < 4; ++kk) {
          float p = hv[kk] * wv[kk];
          acc = acc + p;
        }
      }
      zm[s][j] = (acc + bout[j] > 0.0f) ? 1.0f : 0.0f;
    }
  }
  // (B2's layer entry barrier makes zm visible)

  // ---- B2: dz2 = (mask @ WoutT) * sig(h2) -> registers (K=32) ----
  f4 d0, d1, d2, d3;
  layer_lds<32, false>(WoutT, &zm[0][0], sA, l, tid, wbuf4, a0, a1, a2, a3);
  d0 = sig_ret(a0, &hc[sA + 0][0], l);
  d1 = sig_ret(a1, &hc[sA + 1][0], l);
  d2 = sig_ret(a2, &hc[sA + 2][0], l);
  d3 = sig_ret(a3, &hc[sA + 3][0], l);

  // ---- B1: dz1 = (dz2 @ W2T) * sig(h1) -> registers ----
  layer_reg<256>(W2T, d0, d1, d2, d3, l, tid, wbuf4, a0, a1, a2, a3);
  d0 = sig_ret(a0, &hb[sA + 0][0], l);
  d1 = sig_ret(a1, &hb[sA + 1][0], l);
  d2 = sig_ret(a2, &hb[sA + 2][0], l);
  d3 = sig_ret(a3, &hb[sA + 3][0], l);

  // ---- B0: dz0 = (dz1 @ W1T) * sig(h0) -> ha in-place (BX needs it) ----
  layer_reg<256>(W1T, d0, d1, d2, d3, l, tid, wbuf4, a0, a1, a2, a3);
  sig_store(a0, &ha[sA + 0][0], l);
  sig_store(a1, &ha[sA + 1][0], l);
  sig_store(a2, &ha[sA + 2][0], l);
  sig_store(a3, &ha[sA + 3][0], l);
  __syncthreads();

  // ---- BX: dvdx = dz0 @ W0T -> zm (W0 rows, 32 KB/block, unstaged) ----
  {
    #pragma unroll
    for (int rep = 0; rep < 2; ++rep) {
      int idx = tid + rep * THREADS;
      int s = idx >> 5, j = idx & 31;
      const float* wrow = W0 + (size_t)j * 256;      // W0[j][k]
      float acc = 0.0f;
      #pragma unroll 4
      for (int k = 0; k < 256; k += 4) {
        f4 hv = *(const f4*)&ha[s][k];
        f4 wv = *(const f4*)&wrow[k];
        #pragma unroll
        for (int kk = 0; kk < 4; ++kk) {
          acc = fmaf(hv[kk], wv[kk], acc);
        }
      }
      zm[s][j] = acc;
    }
  }
  __syncthreads();

  // ---- C: c = dvdx @ G -> out ----
  if (tid < SMP * 8) {
    int s = tid >> 3, a = tid & 7;
    float acc = 0.0f;
    #pragma unroll
    for (int j = 0; j < 32; ++j) acc = fmaf(zm[s][j], G[j * 8 + a], acc);
    out[(size_t)(s0 + s) * 8 + a] = acc;
  }
}

// ---------------- BoxCDQP: in-place on d_out (c -> u) ----------------
__global__ __launch_bounds__(256) void k_qp(float* __restrict__ out,
                                            const float* __restrict__ R,
                                            const float* __restrict__ lower,
                                            const float* __restrict__ upper) {
  int t = blockIdx.x * 256 + threadIdx.x;
  float q[8][8], u[8], cc[8], lo[8], hi[8], dg[8];
  #pragma unroll
  for (int i = 0; i < 8; ++i) {
    lo[i] = lower[i];
    hi[i] = upper[i];
    u[i] = 0.0f;
    cc[i] = out[(size_t)t * 8 + i];
    #pragma unroll
    for (int j = 0; j < 8; ++j) q[i][j] = 2.0f * R[i * 8 + j];
  }
  #pragma unroll
  for (int i = 0; i < 8; ++i) dg[i] = q[i][i];

  #pragma unroll 1
  for (int it = 0; it < 30; ++it) {
    #pragma unroll
    for (int i = 0; i < 8; ++i) {
      float g = cc[i];
      #pragma unroll
      for (int j = 0; j < 8; ++j) g = fmaf(q[i][j], u[j], g);
      float v = u[i] - g / dg[i];
      u[i] = fminf(fmaxf(v, lo[i]), hi[i]);
    }
  }
  #pragma unroll
  for (int i = 0; i < 8; ++i) out[(size_t)t * 8 + i] = u[i];
}

extern "C" void kernel_launch(void* const* d_in, const int* in_sizes, int n_in,
                              void* d_out, int out_size, void* d_ws, size_t ws_size,
                              hipStream_t stream) {
  const float* x    = (const float*)d_in[0];
  // d_in[1] = t (unused)
  const float* W0   = (const float*)d_in[2];
  const float* b0   = (const float*)d_in[3];
  const float* W1   = (const float*)d_in[4];
  const float* b1   = (const float*)d_in[5];
  const float* W2   = (const float*)d_in[6];
  const float* b2   = (const float*)d_in[7];
  const float* Wout = (const float*)d_in[8];
  const float* bout = (const float*)d_in[9];
  const float* G    = (const float*)d_in[10];
  const float* R    = (const float*)d_in[11];
  const float* lower= (const float*)d_in[12];
  const float* upper= (const float*)d_in[13];
  float* out = (float*)d_out;
  float* ws  = (float*)d_ws;

  const int B = in_sizes[0] / 32;   // 131072

  k_prep<<<256, 256, 0, stream>>>(W1, W2, Wout, ws);
  k_main<<<B / SMP, THREADS, 0, stream>>>(x, W0, b0, W1, b1, W2, b2,
                                          Wout, bout, G, ws, out);
  k_qp<<<B / 256, 256, 0, stream>>>(out, R, lower, upper);
}

// Round 4
// 2226.802 us; speedup vs baseline: 1.0663x; 1.0663x over previous
//
#include <hip/hip_runtime.h>
#include <math.h>

typedef float f4 __attribute__((ext_vector_type(4)));

#define THREADS 256
#define HID 256
#define SMP 16   // samples per block (4 waves x 4 samples)
#define CH 16    // weight k-rows staged per LDS chunk (16x256 fp32 = 16 KB)

// ---------------- prep: transpose weights into ws ----------------
// ws layout (floats): [0]=W1T 256x256 (W1T[k][n]=W1[n][k]),
//   [65536]=W2T 256x256, [131072]=WoutT 32x256 (WoutT[j][k]=Wout[k][j])
__global__ void k_prep(const float* __restrict__ W1, const float* __restrict__ W2,
                       const float* __restrict__ Wout, float* __restrict__ ws) {
  float* W1T = ws;
  float* W2T = ws + 65536;
  float* WoutT = ws + 131072;
  int tid = blockIdx.x * 256 + threadIdx.x;
  if (tid < 65536) {
    int k = tid >> 8, n = tid & 255;
    W1T[tid] = W1[n * 256 + k];
    W2T[tid] = W2[n * 256 + k];
    if (tid < 8192) {
      int k2 = tid >> 8, n2 = tid & 255;   // WoutT[32][256]
      WoutT[tid] = Wout[n2 * 32 + k2];
    }
  }
}

// softplus = np fp32 semantics (DO NOT TOUCH — mask-critical):
//   sp = max(z,0) + log1pf(expf(-|z|)), each libm call correctly rounded
//   via double intermediates. Verified bit-faithful in rounds 6-8.
__device__ __forceinline__ float sp_cr(float z) {
  float az = fabsf(z);
  float e  = (float)exp(-(double)az);
  float lp = (float)log1p((double)e);
  return fmaxf(z, 0.0f) + lp;
}

// backward factor: sigmoid(z) = 1 - exp(-softplus(z)) from stored activation.
__device__ __forceinline__ float sig_from_h(float h) {
  return 1.0f - __expf(-h);
}

// wave-uniform broadcast of lane ln's value (v_readlane -> SGPR operand).
// Returns bit-identical float -> safe on the exact-forward path.
__device__ __forceinline__ float bcast(float v, int ln) {
  return __uint_as_float(__builtin_amdgcn_readlane(__float_as_uint(v), ln));
}

// ---- forward chunk MAC, h via LDS broadcast (L0 only): exact np order ----
__device__ __forceinline__ void mac_fwd(const float* __restrict__ h0r,
                                        const float* __restrict__ h1r,
                                        const float* __restrict__ h2r,
                                        const float* __restrict__ h3r,
                                        const float* __restrict__ wl,
                                        int l, f4& a0, f4& a1, f4& a2, f4& a3) {
#pragma clang fp contract(off)
  #pragma unroll
  for (int k = 0; k < CH; k += 4) {
    f4 x0 = *(const f4*)&h0r[k];
    f4 x1 = *(const f4*)&h1r[k];
    f4 x2 = *(const f4*)&h2r[k];
    f4 x3 = *(const f4*)&h3r[k];
    #pragma unroll
    for (int kk = 0; kk < 4; ++kk) {
      f4 wv = *(const f4*)&wl[(k + kk) * 256 + l * 4];
      #pragma unroll
      for (int m = 0; m < 4; ++m) { float p = x0[kk] * wv[m]; a0[m] = a0[m] + p; }
      #pragma unroll
      for (int m = 0; m < 4; ++m) { float p = x1[kk] * wv[m]; a1[m] = a1[m] + p; }
      #pragma unroll
      for (int m = 0; m < 4; ++m) { float p = x2[kk] * wv[m]; a2[m] = a2[m] + p; }
      #pragma unroll
      for (int m = 0; m < 4; ++m) { float p = x3[kk] * wv[m]; a3[m] = a3[m] + p; }
    }
  }
}

// ---- backward chunk MAC, input via LDS broadcast (B2 only) ----
__device__ __forceinline__ void mac_bwd(const float* __restrict__ h0r,
                                        const float* __restrict__ h1r,
                                        const float* __restrict__ h2r,
                                        const float* __restrict__ h3r,
                                        const float* __restrict__ wl,
                                        int l, f4& a0, f4& a1, f4& a2, f4& a3) {
  #pragma unroll
  for (int k = 0; k < CH; k += 4) {
    f4 x0 = *(const f4*)&h0r[k];
    f4 x1 = *(const f4*)&h1r[k];
    f4 x2 = *(const f4*)&h2r[k];
    f4 x3 = *(const f4*)&h3r[k];
    #pragma unroll
    for (int kk = 0; kk < 4; ++kk) {
      f4 wv = *(const f4*)&wl[(k + kk) * 256 + l * 4];
      #pragma unroll
      for (int m = 0; m < 4; ++m) a0[m] = fmaf(x0[kk], wv[m], a0[m]);
      #pragma unroll
      for (int m = 0; m < 4; ++m) a1[m] = fmaf(x1[kk], wv[m], a1[m]);
      #pragma unroll
      for (int m = 0; m < 4; ++m) a2[m] = fmaf(x2[kk], wv[m], a2[m]);
      #pragma unroll
      for (int m = 0; m < 4; ++m) a3[m] = fmaf(x3[kk], wv[m], a3[m]);
    }
  }
}

// R2's verified staged K-loop (2 barriers/chunk, reg-prefetch: global loads
// for chunk c+1 issued under mac(c), ds_write after next barrier — latency
// hidden, no explicit vmcnt drains). REG=true: layer input comes from the
// wave's own registers d0..d3 via v_readlane (lane kg>>2 holds col kg's
// value in component kg&3) — removes all 16 h-broadcast LDS reads/chunk.
template <int K, bool FWD, bool REG>
__device__ __forceinline__ void layer(
    const float* __restrict__ Wbase,      // [K][256] row-major
    const float* __restrict__ hin,        // base of [SMP][K]  (REG=false)
    f4 d0, f4 d1, f4 d2, f4 d3,           // wave-local input   (REG=true)
    int sA, int l, int tid, f4* wbuf4, const float* wl,
    f4& a0, f4& a1, f4& a2, f4& a3) {
  a0 = (f4){0, 0, 0, 0}; a1 = a0; a2 = a0; a3 = a0;
  const f4* src = (const f4*)Wbase;
  f4 r0 = src[tid];
  f4 r1 = src[tid + THREADS];
  f4 r2 = src[tid + 2 * THREADS];
  f4 r3 = src[tid + 3 * THREADS];
  constexpr int NC = K / CH;
  #pragma unroll 1
  for (int c = 0; c < NC; ++c) {
    __syncthreads();                       // prev chunk readers / hin writers done
    wbuf4[tid] = r0;
    wbuf4[tid + THREADS] = r1;
    wbuf4[tid + 2 * THREADS] = r2;
    wbuf4[tid + 3 * THREADS] = r3;
    __syncthreads();
    if (c + 1 < NC) {
      const f4* s2 = (const f4*)(Wbase + (size_t)(c + 1) * CH * 256);
      r0 = s2[tid];
      r1 = s2[tid + THREADS];
      r2 = s2[tid + 2 * THREADS];
      r3 = s2[tid + 3 * THREADS];
    }
    if constexpr (REG) {
      if constexpr (FWD) {
#pragma clang fp contract(off)
        #pragma unroll
        for (int kk = 0; kk < CH; ++kk) {
          f4 wv = *(const f4*)&wl[kk * 256 + l * 4];
          int ln = c * 4 + (kk >> 2);      // src lane for kg = c*16+kk
          float b0v = bcast(d0[kk & 3], ln);
          float b1v = bcast(d1[kk & 3], ln);
          float b2v = bcast(d2[kk & 3], ln);
          float b3v = bcast(d3[kk & 3], ln);
          #pragma unroll
          for (int m = 0; m < 4; ++m) { float p = b0v * wv[m]; a0[m] = a0[m] + p; }
          #pragma unroll
          for (int m = 0; m < 4; ++m) { float p = b1v * wv[m]; a1[m] = a1[m] + p; }
          #pragma unroll
          for (int m = 0; m < 4; ++m) { float p = b2v * wv[m]; a2[m] = a2[m] + p; }
          #pragma unroll
          for (int m = 0; m < 4; ++m) { float p = b3v * wv[m]; a3[m] = a3[m] + p; }
        }
      } else {
        #pragma unroll
        for (int kk = 0; kk < CH; ++kk) {
          f4 wv = *(const f4*)&wl[kk * 256 + l * 4];
          int ln = c * 4 + (kk >> 2);
          float b0v = bcast(d0[kk & 3], ln);
          float b1v = bcast(d1[kk & 3], ln);
          float b2v = bcast(d2[kk & 3], ln);
          float b3v = bcast(d3[kk & 3], ln);
          #pragma unroll
          for (int m = 0; m < 4; ++m) a0[m] = fmaf(b0v, wv[m], a0[m]);
          #pragma unroll
          for (int m = 0; m < 4; ++m) a1[m] = fmaf(b1v, wv[m], a1[m]);
          #pragma unroll
          for (int m = 0; m < 4; ++m) a2[m] = fmaf(b2v, wv[m], a2[m]);
          #pragma unroll
          for (int m = 0; m < 4; ++m) a3[m] = fmaf(b3v, wv[m], a3[m]);
        }
      }
    } else {
      const float* h0 = hin + (size_t)(sA + 0) * K + c * CH;
      const float* h1 = hin + (size_t)(sA + 1) * K + c * CH;
      const float* h2 = hin + (size_t)(sA + 2) * K + c * CH;
      const float* h3 = hin + (size_t)(sA + 3) * K + c * CH;
      if constexpr (FWD) mac_fwd(h0, h1, h2, h3, wl, l, a0, a1, a2, a3);
      else               mac_bwd(h0, h1, h2, h3, wl, l, a0, a1, a2, a3);
    }
  }
}

// softplus + store to LDS + return in registers (feeds next layer's readlane)
__device__ __forceinline__ f4 sp_rs(f4 a, const float* __restrict__ b,
                                    float* __restrict__ dstrow, int l) {
  f4 bv = *(const f4*)&b[l * 4];
  f4 o;
  #pragma unroll
  for (int m = 0; m < 4; ++m) o[m] = sp_cr(a[m] + bv[m]);
  *(f4*)&dstrow[l * 4] = o;
  return o;
}

// dz = acc * sig(h) -> registers only (no LDS store)
__device__ __forceinline__ f4 sig_ret(f4 a, const float* __restrict__ hrow, int l) {
  f4 h = *(const f4*)&hrow[l * 4];
  f4 d;
  #pragma unroll
  for (int m = 0; m < 4; ++m) d[m] = a[m] * sig_from_h(h[m]);
  return d;
}

// dz0 must land in LDS for BX's (s,j) mapping
__device__ __forceinline__ void sig_store(f4 a, float* __restrict__ hrow, int l) {
  f4 h = *(f4*)&hrow[l * 4];
  #pragma unroll
  for (int m = 0; m < 4; ++m) h[m] = a[m] * sig_from_h(h[m]);
  *(f4*)&hrow[l * 4] = h;
}

// ---------------- fused MLP fwd (np-faithful) + bwd + c = dvdx@G ------------
// R12 = R2 skeleton (CH=16, reg-prefetch staging, 2 blocks/CU — verified
// 2011 us) + v_readlane input broadcast on all four K=256 layers:
// fwd L1/L2 bit-exact (readlane preserves bits, mul-then-add order kept),
// bwd B1/B0 drop dz stores too. LDS inst/chunk 36 -> 20; fwd flips to
// VALU-bound, bwd LDS time -44%. R3's DMA+vmcnt-drain structure reverted
// (it doubled barrier drains and regressed).
__global__ __launch_bounds__(THREADS, 2) void k_main(
    const float* __restrict__ x,
    const float* __restrict__ W0, const float* __restrict__ b0,
    const float* __restrict__ W1, const float* __restrict__ b1,
    const float* __restrict__ W2, const float* __restrict__ b2,
    const float* __restrict__ Wout, const float* __restrict__ bout,
    const float* __restrict__ G, const float* __restrict__ ws,
    float* __restrict__ out) {
  __shared__ float xs[SMP][32];       // 2 KB
  __shared__ float ha[SMP][HID];      // 16 KB : h0, then dz0
  __shared__ float hb[SMP][HID];      // 16 KB : h1
  __shared__ float hc[SMP][HID];      // 16 KB : h2
  __shared__ float zm[SMP][32];       // 2 KB  : mask, then dvdx
  __shared__ f4 wbuf4[CH * 64];       // 16 KB : staged weight chunk
  float* wl = (float*)wbuf4;

  const float* W1T = ws;
  const float* W2T = ws + 65536;
  const float* WoutT = ws + 131072;

  const int tid = threadIdx.x;
  const int w = tid >> 6;             // wave 0..3 -> samples w*4 .. w*4+3
  const int l = tid & 63;             // cols l*4..l*4+3
  const int sA = w * 4;
  const int s0 = blockIdx.x * SMP;

  for (int i = tid; i < SMP * 32; i += THREADS) {
    xs[i >> 5][i & 31] = x[(size_t)s0 * 32 + i];
  }
  // (layer entry barrier makes xs visible)

  f4 a0, a1, a2, a3;
  f4 o0, o1, o2, o3;                  // forward activation carried in regs
  f4 zz = {0, 0, 0, 0};

  // ---- L0: h0 = softplus(xs @ W0 + b0) -> ha + regs  (K=32, LDS h) ----
  layer<32, true, false>(W0, &xs[0][0], zz, zz, zz, zz, sA, l, tid, wbuf4, wl,
                         a0, a1, a2, a3);
  o0 = sp_rs(a0, b0, &ha[sA + 0][0], l);
  o1 = sp_rs(a1, b0, &ha[sA + 1][0], l);
  o2 = sp_rs(a2, b0, &ha[sA + 2][0], l);
  o3 = sp_rs(a3, b0, &ha[sA + 3][0], l);

  // ---- L1: h1 = softplus(h0 @ W1 + b1) -> hb + regs  (K=256, readlane) ----
  layer<256, true, true>(W1, nullptr, o0, o1, o2, o3, sA, l, tid, wbuf4, wl,
                         a0, a1, a2, a3);
  o0 = sp_rs(a0, b1, &hb[sA + 0][0], l);
  o1 = sp_rs(a1, b1, &hb[sA + 1][0], l);
  o2 = sp_rs(a2, b1, &hb[sA + 2][0], l);
  o3 = sp_rs(a3, b1, &hb[sA + 3][0], l);

  // ---- L2: h2 = softplus(h1 @ W2 + b2) -> hc  (K=256, readlane) ----
  layer<256, true, true>(W2, nullptr, o0, o1, o2, o3, sA, l, tid, wbuf4, wl,
                         a0, a1, a2, a3);
  o0 = sp_rs(a0, b2, &hc[sA + 0][0], l);
  o1 = sp_rs(a1, b2, &hc[sA + 1][0], l);
  o2 = sp_rs(a2, b2, &hc[sA + 2][0], l);
  o3 = sp_rs(a3, b2, &hc[sA + 3][0], l);
  __syncthreads();                     // hc visible to all threads for L3

  // ---- L3: z3 = h2 @ Wout + bout ; mask -> zm (exact np order; WoutT rows,
  // ---- 32 KB/block, cache-resident — unstaged). 512 (s,j) pairs -> 2 reps. --
  {
#pragma clang fp contract(off)
    #pragma unroll
    for (int rep = 0; rep < 2; ++rep) {
      int idx = tid + rep * THREADS;
      int s = idx >> 5, j = idx & 31;
      const float* wrow = WoutT + (size_t)j * 256;   // WoutT[j][k] = Wout[k][j]
      float acc = 0.0f;
      #pragma unroll 4
      for (int k = 0; k < 256; k += 4) {
        f4 hv = *(const f4*)&hc[s][k];
        f4 wv = *(const f4*)&wrow[k];
        #pragma unroll
        for (int kk = 0; kk < 4; ++kk) {
          float p = hv[kk] * wv[kk];
          acc = acc + p;
        }
      }
      zm[s][j] = (acc + bout[j] > 0.0f) ? 1.0f : 0.0f;
    }
  }
  // (B2's layer entry barrier makes zm visible)

  // ---- B2: dz2 = (mask @ WoutT) * sig(h2) -> registers (K=32, LDS zm) ----
  layer<32, false, false>(WoutT, &zm[0][0], zz, zz, zz, zz, sA, l, tid, wbuf4,
                          wl, a0, a1, a2, a3);
  f4 d0 = sig_ret(a0, &hc[sA + 0][0], l);
  f4 d1 = sig_ret(a1, &hc[sA + 1][0], l);
  f4 d2 = sig_ret(a2, &hc[sA + 2][0], l);
  f4 d3 = sig_ret(a3, &hc[sA + 3][0], l);

  // ---- B1: dz1 = (dz2 @ W2T) * sig(h1) -> registers (readlane) ----
  layer<256, false, true>(W2T, nullptr, d0, d1, d2, d3, sA, l, tid, wbuf4, wl,
                          a0, a1, a2, a3);
  d0 = sig_ret(a0, &hb[sA + 0][0], l);
  d1 = sig_ret(a1, &hb[sA + 1][0], l);
  d2 = sig_ret(a2, &hb[sA + 2][0], l);
  d3 = sig_ret(a3, &hb[sA + 3][0], l);

  // ---- B0: dz0 = (dz1 @ W1T) * sig(h0) -> ha in-place (readlane; BX needs
  // ---- dz0 in LDS) ----
  layer<256, false, true>(W1T, nullptr, d0, d1, d2, d3, sA, l, tid, wbuf4, wl,
                          a0, a1, a2, a3);
  sig_store(a0, &ha[sA + 0][0], l);
  sig_store(a1, &ha[sA + 1][0], l);
  sig_store(a2, &ha[sA + 2][0], l);
  sig_store(a3, &ha[sA + 3][0], l);
  __syncthreads();

  // ---- BX: dvdx = dz0 @ W0T -> zm (W0 rows, 32 KB/block, unstaged) ----
  {
    #pragma unroll
    for (int rep = 0; rep < 2; ++rep) {
      int idx = tid + rep * THREADS;
      int s = idx >> 5, j = idx & 31;
      const float* wrow = W0 + (size_t)j * 256;      // W0[j][k]
      float acc = 0.0f;
      #pragma unroll 4
      for (int k = 0; k < 256; k += 4) {
        f4 hv = *(const f4*)&ha[s][k];
        f4 wv = *(const f4*)&wrow[k];
        #pragma unroll
        for (int kk = 0; kk < 4; ++kk) {
          acc = fmaf(hv[kk], wv[kk], acc);
        }
      }
      zm[s][j] = acc;
    }
  }
  __syncthreads();

  // ---- C: c = dvdx @ G -> out ----
  if (tid < SMP * 8) {
    int s = tid >> 3, a = tid & 7;
    float acc = 0.0f;
    #pragma unroll
    for (int j = 0; j < 32; ++j) acc = fmaf(zm[s][j], G[j * 8 + a], acc);
    out[(size_t)(s0 + s) * 8 + a] = acc;
  }
}

// ---------------- BoxCDQP: in-place on d_out (c -> u) ----------------
__global__ __launch_bounds__(256) void k_qp(float* __restrict__ out,
                                            const float* __restrict__ R,
                                            const float* __restrict__ lower,
                                            const float* __restrict__ upper) {
  int t = blockIdx.x * 256 + threadIdx.x;
  float q[8][8], u[8], cc[8], lo[8], hi[8], dg[8];
  #pragma unroll
  for (int i = 0; i < 8; ++i) {
    lo[i] = lower[i];
    hi[i] = upper[i];
    u[i] = 0.0f;
    cc[i] = out[(size_t)t * 8 + i];
    #pragma unroll
    for (int j = 0; j < 8; ++j) q[i][j] = 2.0f * R[i * 8 + j];
  }
  #pragma unroll
  for (int i = 0; i < 8; ++i) dg[i] = q[i][i];

  #pragma unroll 1
  for (int it = 0; it < 30; ++it) {
    #pragma unroll
    for (int i = 0; i < 8; ++i) {
      float g = cc[i];
      #pragma unroll
      for (int j = 0; j < 8; ++j) g = fmaf(q[i][j], u[j], g);
      float v = u[i] - g / dg[i];
      u[i] = fminf(fmaxf(v, lo[i]), hi[i]);
    }
  }
  #pragma unroll
  for (int i = 0; i < 8; ++i) out[(size_t)t * 8 + i] = u[i];
}

extern "C" void kernel_launch(void* const* d_in, const int* in_sizes, int n_in,
                              void* d_out, int out_size, void* d_ws, size_t ws_size,
                              hipStream_t stream) {
  const float* x    = (const float*)d_in[0];
  // d_in[1] = t (unused)
  const float* W0   = (const float*)d_in[2];
  const float* b0   = (const float*)d_in[3];
  const float* W1   = (const float*)d_in[4];
  const float* b1   = (const float*)d_in[5];
  const float* W2   = (const float*)d_in[6];
  const float* b2   = (const float*)d_in[7];
  const float* Wout = (const float*)d_in[8];
  const float* bout = (const float*)d_in[9];
  const float* G    = (const float*)d_in[10];
  const float* R    = (const float*)d_in[11];
  const float* lower= (const float*)d_in[12];
  const float* upper= (const float*)d_in[13];
  float* out = (float*)d_out;
  float* ws  = (float*)d_ws;

  const int B = in_sizes[0] / 32;   // 131072

  k_prep<<<256, 256, 0, stream>>>(W1, W2, Wout, ws);
  k_main<<<B / SMP, THREADS, 0, stream>>>(x, W0, b0, W1, b1, W2, b2,
                                          Wout, bout, G, ws, out);
  k_qp<<<B / 256, 256, 0, stream>>>(out, R, lower, upper);
}

// Round 5
// 2127.134 us; speedup vs baseline: 1.1162x; 1.0469x over previous
//
#include <hip/hip_runtime.h>
#include <math.h>

typedef float f4 __attribute__((ext_vector_type(4)));
typedef float f2 __attribute__((ext_vector_type(2)));

#define THREADS 256
#define HID 256
#define SMP 16   // samples per block (4 waves x 4 samples)

// ---------------- prep: transpose weights into ws ----------------
// ws layout (floats): [0]=W1T 256x256 (W1T[k][n]=W1[n][k]),
//   [65536]=W2T 256x256, [131072]=WoutT 32x256 (WoutT[j][k]=Wout[k][j])
__global__ void k_prep(const float* __restrict__ W1, const float* __restrict__ W2,
                       const float* __restrict__ Wout, float* __restrict__ ws) {
  float* W1T = ws;
  float* W2T = ws + 65536;
  float* WoutT = ws + 131072;
  int tid = blockIdx.x * 256 + threadIdx.x;
  if (tid < 65536) {
    int k = tid >> 8, n = tid & 255;
    W1T[tid] = W1[n * 256 + k];
    W2T[tid] = W2[n * 256 + k];
    if (tid < 8192) {
      int k2 = tid >> 8, n2 = tid & 255;   // WoutT[32][256]
      WoutT[tid] = Wout[n2 * 32 + k2];
    }
  }
}

// softplus = np fp32 semantics (DO NOT TOUCH — mask-critical):
//   sp = max(z,0) + log1pf(expf(-|z|)), each libm call correctly rounded
//   via double intermediates. Verified bit-faithful in rounds 6-8.
__device__ __forceinline__ float sp_cr(float z) {
  float az = fabsf(z);
  float e  = (float)exp(-(double)az);
  float lp = (float)log1p((double)e);
  return fmaxf(z, 0.0f) + lp;
}

// backward factor: sigmoid(z) = 1 - exp(-softplus(z)) from stored activation.
__device__ __forceinline__ float sig_from_h(float h) {
  return 1.0f - __expf(-h);
}

// ---------------- packed-fp32 MAC primitives (VOP3P) ----------------
// v_pk_* f32 ops = two independent IEEE fp32 ops, identical rounding to
// scalar v_mul/v_add/v_fma -> bit-identical results at half the inst count.
// op_sel broadcasts one component of the h pair to both halves (no movs).

// d = (h[SEL] * w.lo, h[SEL] * w.hi)
template <int SEL>
__device__ __forceinline__ f2 pk_mul_b(f2 h, f2 w) {
  f2 d;
  if constexpr (SEL == 0)
    asm("v_pk_mul_f32 %0, %1, %2 op_sel:[0,0] op_sel_hi:[0,1]"
        : "=v"(d) : "v"(h), "v"(w));
  else
    asm("v_pk_mul_f32 %0, %1, %2 op_sel:[1,0] op_sel_hi:[1,1]"
        : "=v"(d) : "v"(h), "v"(w));
  return d;
}

__device__ __forceinline__ f2 pk_add(f2 a, f2 b) {
  f2 d;
  asm("v_pk_add_f32 %0, %1, %2" : "=v"(d) : "v"(a), "v"(b));
  return d;
}

// a += (h[SEL] * w.lo, h[SEL] * w.hi)   (fma rounding, bwd path)
template <int SEL>
__device__ __forceinline__ void pk_fma_b(f2& a, f2 h, f2 w) {
  if constexpr (SEL == 0)
    asm("v_pk_fma_f32 %0, %1, %2, %0 op_sel:[0,0,0] op_sel_hi:[0,1,1]"
        : "+v"(a) : "v"(h), "v"(w));
  else
    asm("v_pk_fma_f32 %0, %1, %2, %0 op_sel:[1,0,0] op_sel_hi:[1,1,1]"
        : "+v"(a) : "v"(h), "v"(w));
}

// 4 MACs (one k, one sample, 4 cols) using h component SEL of pair hp.
// FWD: mul-then-add separate rounding (np-exact); BWD: fmaf.
template <bool FWD, int SEL>
__device__ __forceinline__ void mac4(f2 (&a)[2], f2 hp, f4 wq) {
  f2 w01 = __builtin_shufflevector(wq, wq, 0, 1);
  f2 w23 = __builtin_shufflevector(wq, wq, 2, 3);
  if constexpr (FWD) {
    a[0] = pk_add(a[0], pk_mul_b<SEL>(hp, w01));
    a[1] = pk_add(a[1], pk_mul_b<SEL>(hp, w23));
  } else {
    pk_fma_b<SEL>(a[0], hp, w01);
    pk_fma_b<SEL>(a[1], hp, w23);
  }
}

// ---------------- layer: weights streamed from global (L2-resident) --------
// No LDS staging, no intra-layer barriers: each wave reads the full weight
// panel via coalesced dwordx4 (64 lanes x 16B = 1KB/inst), h rows via
// wave-uniform LDS broadcast. Per-element summation order: ascending k,
// identical to the staged R2 kernel -> bit-identical output.
template <int K, bool FWD>
__device__ __forceinline__ void layer_g(const float* __restrict__ Wbase,
                                        const float* __restrict__ hin,
                                        int sA, int l, f2 (&acc)[4][2]) {
  #pragma unroll
  for (int s = 0; s < 4; ++s) {
    acc[s][0] = (f2){0.f, 0.f};
    acc[s][1] = (f2){0.f, 0.f};
  }
  const float* wp = Wbase + l * 4;
  #pragma unroll 4
  for (int k4 = 0; k4 < K; k4 += 4) {
    f4 wq0 = *(const f4*)(wp + (k4 + 0) * 256);
    f4 wq1 = *(const f4*)(wp + (k4 + 1) * 256);
    f4 wq2 = *(const f4*)(wp + (k4 + 2) * 256);
    f4 wq3 = *(const f4*)(wp + (k4 + 3) * 256);
    #pragma unroll
    for (int s = 0; s < 4; ++s) {
      f4 hq = *(const f4*)&hin[(sA + s) * K + k4];
      f2 h01 = __builtin_shufflevector(hq, hq, 0, 1);
      f2 h23 = __builtin_shufflevector(hq, hq, 2, 3);
      mac4<FWD, 0>(acc[s], h01, wq0);   // k = k4+0
      mac4<FWD, 1>(acc[s], h01, wq1);   // k = k4+1
      mac4<FWD, 0>(acc[s], h23, wq2);   // k = k4+2
      mac4<FWD, 1>(acc[s], h23, wq3);   // k = k4+3
    }
  }
}

// softplus(acc + b) -> LDS row (scalar adds, same order/rounding as before)
__device__ __forceinline__ void sp_store(const f2 (&a)[2],
                                         const float* __restrict__ b,
                                         float* __restrict__ dstrow, int l) {
  f4 bv = *(const f4*)&b[l * 4];
  f4 o;
  o[0] = sp_cr(a[0][0] + bv[0]);
  o[1] = sp_cr(a[0][1] + bv[1]);
  o[2] = sp_cr(a[1][0] + bv[2]);
  o[3] = sp_cr(a[1][1] + bv[3]);
  *(f4*)&dstrow[l * 4] = o;
}

// dz = acc * sig(h) -> LDS row in-place
__device__ __forceinline__ void sig_store(const f2 (&a)[2],
                                          float* __restrict__ hrow, int l) {
  f4 h = *(f4*)&hrow[l * 4];
  f4 d;
  d[0] = a[0][0] * sig_from_h(h[0]);
  d[1] = a[0][1] * sig_from_h(h[1]);
  d[2] = a[1][0] * sig_from_h(h[2]);
  d[3] = a[1][1] * sig_from_h(h[3]);
  *(f4*)&hrow[l * 4] = d;
}

// ---------------- fused MLP fwd (np-faithful) + bwd + c = dvdx@G ------------
// R13: (1) packed-fp32 MACs via v_pk_*+op_sel (bit-identical, half the VALU
// inst — R4 showed VALU is the binding pipe at 1815 us busy), (2) weights
// streamed directly from L2 (no wbuf, no staging ds ops, barriers 200 -> 5;
// waves drift freely through layers since all MAC inputs are own-wave LDS
// rows), (3) 52 KB LDS -> 3 blocks/CU for L2-latency hiding.
// Output must be bit-identical to R2 (absmax 0.0004882812) — regression check.
__global__ __launch_bounds__(THREADS, 3) void k_main(
    const float* __restrict__ x,
    const float* __restrict__ W0, const float* __restrict__ b0,
    const float* __restrict__ W1, const float* __restrict__ b1,
    const float* __restrict__ W2, const float* __restrict__ b2,
    const float* __restrict__ Wout, const float* __restrict__ bout,
    const float* __restrict__ G, const float* __restrict__ ws,
    float* __restrict__ out) {
  __shared__ float xs[SMP][32];       // 2 KB
  __shared__ float ha[SMP][HID];      // 16 KB : h0, then dz0
  __shared__ float hb[SMP][HID];      // 16 KB : h1, then dz1
  __shared__ float hc[SMP][HID];      // 16 KB : h2, then dz2
  __shared__ float zm[SMP][32];       // 2 KB  : mask, then dvdx

  const float* W1T = ws;
  const float* W2T = ws + 65536;
  const float* WoutT = ws + 131072;

  const int tid = threadIdx.x;
  const int w = tid >> 6;             // wave 0..3 -> samples w*4 .. w*4+3
  const int l = tid & 63;             // cols l*4..l*4+3
  const int sA = w * 4;
  const int s0 = blockIdx.x * SMP;

  for (int i = tid; i < SMP * 32; i += THREADS) {
    xs[i >> 5][i & 31] = x[(size_t)s0 * 32 + i];
  }
  __syncthreads();                    // xs visible

  f2 acc[4][2];

  // ---- L0: h0 = softplus(xs @ W0 + b0) -> ha  (K=32) ----
  layer_g<32, true>(W0, &xs[0][0], sA, l, acc);
  sp_store(acc[0], b0, &ha[sA + 0][0], l);
  sp_store(acc[1], b0, &ha[sA + 1][0], l);
  sp_store(acc[2], b0, &ha[sA + 2][0], l);
  sp_store(acc[3], b0, &ha[sA + 3][0], l);
  // own-wave rows only -> no barrier (same-wave LDS RAW ordered by lgkmcnt)

  // ---- L1: h1 = softplus(h0 @ W1 + b1) -> hb  (K=256) ----
  layer_g<256, true>(W1, &ha[0][0], sA, l, acc);
  sp_store(acc[0], b1, &hb[sA + 0][0], l);
  sp_store(acc[1], b1, &hb[sA + 1][0], l);
  sp_store(acc[2], b1, &hb[sA + 2][0], l);
  sp_store(acc[3], b1, &hb[sA + 3][0], l);

  // ---- L2: h2 = softplus(h1 @ W2 + b2) -> hc ----
  layer_g<256, true>(W2, &hb[0][0], sA, l, acc);
  sp_store(acc[0], b2, &hc[sA + 0][0], l);
  sp_store(acc[1], b2, &hc[sA + 1][0], l);
  sp_store(acc[2], b2, &hc[sA + 2][0], l);
  sp_store(acc[3], b2, &hc[sA + 3][0], l);
  __syncthreads();                    // hc all rows for L3 (cross-wave)

  // ---- L3: z3 = h2 @ Wout + bout ; mask -> zm (exact np order; WoutT rows,
  // ---- cache-resident). 512 (s,j) pairs -> 2 reps. ----
  {
#pragma clang fp contract(off)
    #pragma unroll
    for (int rep = 0; rep < 2; ++rep) {
      int idx = tid + rep * THREADS;
      int s = idx >> 5, j = idx & 31;
      const float* wrow = WoutT + (size_t)j * 256;   // WoutT[j][k] = Wout[k][j]
      float acc0 = 0.0f;
      #pragma unroll 4
      for (int k = 0; k < 256; k += 4) {
        f4 hv = *(const f4*)&hc[s][k];
        f4 wv = *(const f4*)&wrow[k];
        #pragma unroll
        for (int kk = 0; kk < 4; ++kk) {
          float p = hv[kk] * wv[kk];
          acc0 = acc0 + p;
        }
      }
      zm[s][j] = (acc0 + bout[j] > 0.0f) ? 1.0f : 0.0f;
    }
  }
  __syncthreads();                    // zm visible to B2 (cross-wave rows)

  // ---- B2: dz2 = (mask @ WoutT) * sig(h2) -> hc in-place (K=32) ----
  layer_g<32, false>(WoutT, &zm[0][0], sA, l, acc);
  sig_store(acc[0], &hc[sA + 0][0], l);
  sig_store(acc[1], &hc[sA + 1][0], l);
  sig_store(acc[2], &hc[sA + 2][0], l);
  sig_store(acc[3], &hc[sA + 3][0], l);

  // ---- B1: dz1 = (dz2 @ W2T) * sig(h1) -> hb in-place ----
  layer_g<256, false>(W2T, &hc[0][0], sA, l, acc);
  sig_store(acc[0], &hb[sA + 0][0], l);
  sig_store(acc[1], &hb[sA + 1][0], l);
  sig_store(acc[2], &hb[sA + 2][0], l);
  sig_store(acc[3], &hb[sA + 3][0], l);

  // ---- B0: dz0 = (dz1 @ W1T) * sig(h0) -> ha in-place ----
  layer_g<256, false>(W1T, &hb[0][0], sA, l, acc);
  sig_store(acc[0], &ha[sA + 0][0], l);
  sig_store(acc[1], &ha[sA + 1][0], l);
  sig_store(acc[2], &ha[sA + 2][0], l);
  sig_store(acc[3], &ha[sA + 3][0], l);
  __syncthreads();                    // ha = dz0 all rows for BX (cross-wave)

  // ---- BX: dvdx = dz0 @ W0T -> zm (W0 rows, cache-resident) ----
  {
    #pragma unroll
    for (int rep = 0; rep < 2; ++rep) {
      int idx = tid + rep * THREADS;
      int s = idx >> 5, j = idx & 31;
      const float* wrow = W0 + (size_t)j * 256;      // W0[j][k]
      float acc0 = 0.0f;
      #pragma unroll 4
      for (int k = 0; k < 256; k += 4) {
        f4 hv = *(const f4*)&ha[s][k];
        f4 wv = *(const f4*)&wrow[k];
        #pragma unroll
        for (int kk = 0; kk < 4; ++kk) {
          acc0 = fmaf(hv[kk], wv[kk], acc0);
        }
      }
      zm[s][j] = acc0;
    }
  }
  __syncthreads();                    // zm = dvdx for C

  // ---- C: c = dvdx @ G -> out ----
  if (tid < SMP * 8) {
    int s = tid >> 3, a = tid & 7;
    float acc0 = 0.0f;
    #pragma unroll
    for (int j = 0; j < 32; ++j) acc0 = fmaf(zm[s][j], G[j * 8 + a], acc0);
    out[(size_t)(s0 + s) * 8 + a] = acc0;
  }
}

// ---------------- BoxCDQP: in-place on d_out (c -> u) ----------------
__global__ __launch_bounds__(256) void k_qp(float* __restrict__ out,
                                            const float* __restrict__ R,
                                            const float* __restrict__ lower,
                                            const float* __restrict__ upper) {
  int t = blockIdx.x * 256 + threadIdx.x;
  float q[8][8], u[8], cc[8], lo[8], hi[8], dg[8];
  #pragma unroll
  for (int i = 0; i < 8; ++i) {
    lo[i] = lower[i];
    hi[i] = upper[i];
    u[i] = 0.0f;
    cc[i] = out[(size_t)t * 8 + i];
    #pragma unroll
    for (int j = 0; j < 8; ++j) q[i][j] = 2.0f * R[i * 8 + j];
  }
  #pragma unroll
  for (int i = 0; i < 8; ++i) dg[i] = q[i][i];

  #pragma unroll 1
  for (int it = 0; it < 30; ++it) {
    #pragma unroll
    for (int i = 0; i < 8; ++i) {
      float g = cc[i];
      #pragma unroll
      for (int j = 0; j < 8; ++j) g = fmaf(q[i][j], u[j], g);
      float v = u[i] - g / dg[i];
      u[i] = fminf(fmaxf(v, lo[i]), hi[i]);
    }
  }
  #pragma unroll
  for (int i = 0; i < 8; ++i) out[(size_t)t * 8 + i] = u[i];
}

extern "C" void kernel_launch(void* const* d_in, const int* in_sizes, int n_in,
                              void* d_out, int out_size, void* d_ws, size_t ws_size,
                              hipStream_t stream) {
  const float* x    = (const float*)d_in[0];
  // d_in[1] = t (unused)
  const float* W0   = (const float*)d_in[2];
  const float* b0   = (const float*)d_in[3];
  const float* W1   = (const float*)d_in[4];
  const float* b1   = (const float*)d_in[5];
  const float* W2   = (const float*)d_in[6];
  const float* b2   = (const float*)d_in[7];
  const float* Wout = (const float*)d_in[8];
  const float* bout = (const float*)d_in[9];
  const float* G    = (const float*)d_in[10];
  const float* R    = (const float*)d_in[11];
  const float* lower= (const float*)d_in[12];
  const float* upper= (const float*)d_in[13];
  float* out = (float*)d_out;
  float* ws  = (float*)d_ws;

  const int B = in_sizes[0] / 32;   // 131072

  k_prep<<<256, 256, 0, stream>>>(W1, W2, Wout, ws);
  k_main<<<B / SMP, THREADS, 0, stream>>>(x, W0, b0, W1, b1, W2, b2,
                                          Wout, bout, G, ws, out);
  k_qp<<<B / 256, 256, 0, stream>>>(out, R, lower, upper);
}

// Round 6
// 2105.200 us; speedup vs baseline: 1.1279x; 1.0104x over previous
//
#include <hip/hip_runtime.h>
#include <math.h>

typedef float f4 __attribute__((ext_vector_type(4)));
typedef float f2 __attribute__((ext_vector_type(2)));

#define THREADS 256
#define HID 256
#define SMP 16   // samples per block (4 waves x 4 samples)

// ---------------- prep: transpose weights into ws ----------------
// ws layout (floats): [0]=W1T 256x256 (W1T[k][n]=W1[n][k]),
//   [65536]=W2T 256x256, [131072]=WoutT 32x256 (WoutT[j][k]=Wout[k][j])
__global__ void k_prep(const float* __restrict__ W1, const float* __restrict__ W2,
                       const float* __restrict__ Wout, float* __restrict__ ws) {
  float* W1T = ws;
  float* W2T = ws + 65536;
  float* WoutT = ws + 131072;
  int tid = blockIdx.x * 256 + threadIdx.x;
  if (tid < 65536) {
    int k = tid >> 8, n = tid & 255;
    W1T[tid] = W1[n * 256 + k];
    W2T[tid] = W2[n * 256 + k];
    if (tid < 8192) {
      int k2 = tid >> 8, n2 = tid & 255;   // WoutT[32][256]
      WoutT[tid] = Wout[n2 * 32 + k2];
    }
  }
}

// softplus = np fp32 semantics (DO NOT TOUCH — mask-critical):
//   sp = max(z,0) + log1pf(expf(-|z|)), each libm call correctly rounded
//   via double intermediates. Verified bit-faithful in rounds 6-8.
__device__ __forceinline__ float sp_cr(float z) {
  float az = fabsf(z);
  float e  = (float)exp(-(double)az);
  float lp = (float)log1p((double)e);
  return fmaxf(z, 0.0f) + lp;
}

// backward factor: sigmoid(z) = 1 - exp(-softplus(z)) from stored activation.
__device__ __forceinline__ float sig_from_h(float h) {
  return 1.0f - __expf(-h);
}

// ---------------- packed-fp32 MAC primitives (VOP3P) ----------------
// v_pk_* f32 ops = two independent IEEE fp32 ops, identical rounding to
// scalar v_mul/v_add/v_fma -> bit-identical results at half the inst count.
// op_sel broadcasts one component of the h pair to both halves (no movs).

// d = (h[SEL] * w.lo, h[SEL] * w.hi)
template <int SEL>
__device__ __forceinline__ f2 pk_mul_b(f2 h, f2 w) {
  f2 d;
  if constexpr (SEL == 0)
    asm("v_pk_mul_f32 %0, %1, %2 op_sel:[0,0] op_sel_hi:[0,1]"
        : "=v"(d) : "v"(h), "v"(w));
  else
    asm("v_pk_mul_f32 %0, %1, %2 op_sel:[1,0] op_sel_hi:[1,1]"
        : "=v"(d) : "v"(h), "v"(w));
  return d;
}

__device__ __forceinline__ f2 pk_add(f2 a, f2 b) {
  f2 d;
  asm("v_pk_add_f32 %0, %1, %2" : "=v"(d) : "v"(a), "v"(b));
  return d;
}

// a += (h[SEL] * w.lo, h[SEL] * w.hi)   (fma rounding, bwd path)
template <int SEL>
__device__ __forceinline__ void pk_fma_b(f2& a, f2 h, f2 w) {
  if constexpr (SEL == 0)
    asm("v_pk_fma_f32 %0, %1, %2, %0 op_sel:[0,0,0] op_sel_hi:[0,1,1]"
        : "+v"(a) : "v"(h), "v"(w));
  else
    asm("v_pk_fma_f32 %0, %1, %2, %0 op_sel:[1,0,0] op_sel_hi:[1,1,1]"
        : "+v"(a) : "v"(h), "v"(w));
}

// 4 MACs (one k, one sample, 4 cols) using h component SEL of pair hp.
// FWD: mul-then-add separate rounding (np-exact); BWD: fmaf.
template <bool FWD, int SEL>
__device__ __forceinline__ void mac4(f2 (&a)[2], f2 hp, f4 wq) {
  f2 w01 = __builtin_shufflevector(wq, wq, 0, 1);
  f2 w23 = __builtin_shufflevector(wq, wq, 2, 3);
  if constexpr (FWD) {
    a[0] = pk_add(a[0], pk_mul_b<SEL>(hp, w01));
    a[1] = pk_add(a[1], pk_mul_b<SEL>(hp, w23));
  } else {
    pk_fma_b<SEL>(a[0], hp, w01);
    pk_fma_b<SEL>(a[1], hp, w23);
  }
}

// MAC one 8-k-row pair (k = 8p..8p+7, ascending — np-exact order) for all
// 4 samples, weights from the named register bank wv[8].
template <int K, bool FWD>
__device__ __forceinline__ void mac_pair(f2 (&acc)[4][2],
                                         const float* __restrict__ hin,
                                         int sA, int p, const f4 (&wv)[8]) {
  #pragma unroll
  for (int s = 0; s < 4; ++s) {
    const float* hrow = &hin[(size_t)(sA + s) * K + p * 8];
    f4 hq0 = *(const f4*)&hrow[0];
    f4 hq1 = *(const f4*)&hrow[4];
    f2 h01 = __builtin_shufflevector(hq0, hq0, 0, 1);
    f2 h23 = __builtin_shufflevector(hq0, hq0, 2, 3);
    f2 h45 = __builtin_shufflevector(hq1, hq1, 0, 1);
    f2 h67 = __builtin_shufflevector(hq1, hq1, 2, 3);
    mac4<FWD, 0>(acc[s], h01, wv[0]);   // k = 8p+0
    mac4<FWD, 1>(acc[s], h01, wv[1]);   // k = 8p+1
    mac4<FWD, 0>(acc[s], h23, wv[2]);   // k = 8p+2
    mac4<FWD, 1>(acc[s], h23, wv[3]);   // k = 8p+3
    mac4<FWD, 0>(acc[s], h45, wv[4]);   // k = 8p+4
    mac4<FWD, 1>(acc[s], h45, wv[5]);   // k = 8p+5
    mac4<FWD, 0>(acc[s], h67, wv[6]);   // k = 8p+6
    mac4<FWD, 1>(acc[s], h67, wv[7]);   // k = 8p+7
  }
}

// ---------------- layer: weights streamed from L2 with register dbuf --------
// T14 split: issue the NEXT pair's 8 dwordx4 loads into the alternate named
// bank (wA/wB — static indexing, no scratch), then MAC the current bank.
// Compiler emits counted vmcnt(8) before each MAC group -> L2 latency hides
// under the 128-inst MAC body (R5 exposed it: VALUBusy 53%, wall 2570).
// h rows via wave-uniform LDS broadcast. Per-element summation order:
// ascending k, identical to R2/R5 -> bit-identical output.
template <int K, bool FWD>
__device__ __forceinline__ void layer_g(const float* __restrict__ Wbase,
                                        const float* __restrict__ hin,
                                        int sA, int l, f2 (&acc)[4][2]) {
  #pragma unroll
  for (int s = 0; s < 4; ++s) {
    acc[s][0] = (f2){0.f, 0.f};
    acc[s][1] = (f2){0.f, 0.f};
  }
  const float* wp = Wbase + l * 4;
  constexpr int NP = K / 8;            // 8-row pairs (NP even: 4 or 32)
  f4 wA[8], wB[8];
  #pragma unroll
  for (int j = 0; j < 8; ++j) wA[j] = *(const f4*)(wp + j * 256);
  #pragma unroll 1
  for (int p = 0; p < NP; p += 2) {
    const float* wn1 = wp + (size_t)(p + 1) * 8 * 256;
    #pragma unroll
    for (int j = 0; j < 8; ++j) wB[j] = *(const f4*)(wn1 + j * 256);
    mac_pair<K, FWD>(acc, hin, sA, p, wA);
    if (p + 2 < NP) {
      const float* wn2 = wp + (size_t)(p + 2) * 8 * 256;
      #pragma unroll
      for (int j = 0; j < 8; ++j) wA[j] = *(const f4*)(wn2 + j * 256);
    }
    mac_pair<K, FWD>(acc, hin, sA, p + 1, wB);
  }
}

// softplus(acc + b) -> LDS row (scalar adds, same order/rounding as before)
__device__ __forceinline__ void sp_store(const f2 (&a)[2],
                                         const float* __restrict__ b,
                                         float* __restrict__ dstrow, int l) {
  f4 bv = *(const f4*)&b[l * 4];
  f4 o;
  o[0] = sp_cr(a[0][0] + bv[0]);
  o[1] = sp_cr(a[0][1] + bv[1]);
  o[2] = sp_cr(a[1][0] + bv[2]);
  o[3] = sp_cr(a[1][1] + bv[3]);
  *(f4*)&dstrow[l * 4] = o;
}

// dz = acc * sig(h) -> LDS row in-place
__device__ __forceinline__ void sig_store(const f2 (&a)[2],
                                          float* __restrict__ hrow, int l) {
  f4 h = *(f4*)&hrow[l * 4];
  f4 d;
  d[0] = a[0][0] * sig_from_h(h[0]);
  d[1] = a[0][1] * sig_from_h(h[1]);
  d[2] = a[1][0] * sig_from_h(h[2]);
  d[3] = a[1][1] * sig_from_h(h[3]);
  *(f4*)&hrow[l * 4] = d;
}

// ---------------- fused MLP fwd (np-faithful) + bwd + c = dvdx@G ------------
// R14 = R5 (packed MACs, L2-streamed weights, barrier-light, 3 blocks/CU)
// + register double-buffer prefetch of the weight panels (the one change).
// Output must be bit-identical (absmax 0.0004882812) — regression check.
__global__ __launch_bounds__(THREADS, 3) void k_main(
    const float* __restrict__ x,
    const float* __restrict__ W0, const float* __restrict__ b0,
    const float* __restrict__ W1, const float* __restrict__ b1,
    const float* __restrict__ W2, const float* __restrict__ b2,
    const float* __restrict__ Wout, const float* __restrict__ bout,
    const float* __restrict__ G, const float* __restrict__ ws,
    float* __restrict__ out) {
  __shared__ float xs[SMP][32];       // 2 KB
  __shared__ float ha[SMP][HID];      // 16 KB : h0, then dz0
  __shared__ float hb[SMP][HID];      // 16 KB : h1, then dz1
  __shared__ float hc[SMP][HID];      // 16 KB : h2, then dz2
  __shared__ float zm[SMP][32];       // 2 KB  : mask, then dvdx

  const float* W1T = ws;
  const float* W2T = ws + 65536;
  const float* WoutT = ws + 131072;

  const int tid = threadIdx.x;
  const int w = tid >> 6;             // wave 0..3 -> samples w*4 .. w*4+3
  const int l = tid & 63;             // cols l*4..l*4+3
  const int sA = w * 4;
  const int s0 = blockIdx.x * SMP;

  for (int i = tid; i < SMP * 32; i += THREADS) {
    xs[i >> 5][i & 31] = x[(size_t)s0 * 32 + i];
  }
  __syncthreads();                    // xs visible

  f2 acc[4][2];

  // ---- L0: h0 = softplus(xs @ W0 + b0) -> ha  (K=32) ----
  layer_g<32, true>(W0, &xs[0][0], sA, l, acc);
  sp_store(acc[0], b0, &ha[sA + 0][0], l);
  sp_store(acc[1], b0, &ha[sA + 1][0], l);
  sp_store(acc[2], b0, &ha[sA + 2][0], l);
  sp_store(acc[3], b0, &ha[sA + 3][0], l);
  // own-wave rows only -> no barrier (same-wave LDS RAW ordered by lgkmcnt)

  // ---- L1: h1 = softplus(h0 @ W1 + b1) -> hb  (K=256) ----
  layer_g<256, true>(W1, &ha[0][0], sA, l, acc);
  sp_store(acc[0], b1, &hb[sA + 0][0], l);
  sp_store(acc[1], b1, &hb[sA + 1][0], l);
  sp_store(acc[2], b1, &hb[sA + 2][0], l);
  sp_store(acc[3], b1, &hb[sA + 3][0], l);

  // ---- L2: h2 = softplus(h1 @ W2 + b2) -> hc ----
  layer_g<256, true>(W2, &hb[0][0], sA, l, acc);
  sp_store(acc[0], b2, &hc[sA + 0][0], l);
  sp_store(acc[1], b2, &hc[sA + 1][0], l);
  sp_store(acc[2], b2, &hc[sA + 2][0], l);
  sp_store(acc[3], b2, &hc[sA + 3][0], l);
  __syncthreads();                    // hc all rows for L3 (cross-wave)

  // ---- L3: z3 = h2 @ Wout + bout ; mask -> zm (exact np order; WoutT rows,
  // ---- cache-resident). 512 (s,j) pairs -> 2 reps. ----
  {
#pragma clang fp contract(off)
    #pragma unroll
    for (int rep = 0; rep < 2; ++rep) {
      int idx = tid + rep * THREADS;
      int s = idx >> 5, j = idx & 31;
      const float* wrow = WoutT + (size_t)j * 256;   // WoutT[j][k] = Wout[k][j]
      float acc0 = 0.0f;
      #pragma unroll 4
      for (int k = 0; k < 256; k += 4) {
        f4 hv = *(const f4*)&hc[s][k];
        f4 wv = *(const f4*)&wrow[k];
        #pragma unroll
        for (int kk = 0; kk < 4; ++kk) {
          float p = hv[kk] * wv[kk];
          acc0 = acc0 + p;
        }
      }
      zm[s][j] = (acc0 + bout[j] > 0.0f) ? 1.0f : 0.0f;
    }
  }
  __syncthreads();                    // zm visible to B2 (cross-wave rows)

  // ---- B2: dz2 = (mask @ WoutT) * sig(h2) -> hc in-place (K=32) ----
  layer_g<32, false>(WoutT, &zm[0][0], sA, l, acc);
  sig_store(acc[0], &hc[sA + 0][0], l);
  sig_store(acc[1], &hc[sA + 1][0], l);
  sig_store(acc[2], &hc[sA + 2][0], l);
  sig_store(acc[3], &hc[sA + 3][0], l);

  // ---- B1: dz1 = (dz2 @ W2T) * sig(h1) -> hb in-place ----
  layer_g<256, false>(W2T, &hc[0][0], sA, l, acc);
  sig_store(acc[0], &hb[sA + 0][0], l);
  sig_store(acc[1], &hb[sA + 1][0], l);
  sig_store(acc[2], &hb[sA + 2][0], l);
  sig_store(acc[3], &hb[sA + 3][0], l);

  // ---- B0: dz0 = (dz1 @ W1T) * sig(h0) -> ha in-place ----
  layer_g<256, false>(W1T, &hb[0][0], sA, l, acc);
  sig_store(acc[0], &ha[sA + 0][0], l);
  sig_store(acc[1], &ha[sA + 1][0], l);
  sig_store(acc[2], &ha[sA + 2][0], l);
  sig_store(acc[3], &ha[sA + 3][0], l);
  __syncthreads();                    // ha = dz0 all rows for BX (cross-wave)

  // ---- BX: dvdx = dz0 @ W0T -> zm (W0 rows, cache-resident) ----
  {
    #pragma unroll
    for (int rep = 0; rep < 2; ++rep) {
      int idx = tid + rep * THREADS;
      int s = idx >> 5, j = idx & 31;
      const float* wrow = W0 + (size_t)j * 256;      // W0[j][k]
      float acc0 = 0.0f;
      #pragma unroll 4
      for (int k = 0; k < 256; k += 4) {
        f4 hv = *(const f4*)&ha[s][k];
        f4 wv = *(const f4*)&wrow[k];
        #pragma unroll
        for (int kk = 0; kk < 4; ++kk) {
          acc0 = fmaf(hv[kk], wv[kk], acc0);
        }
      }
      zm[s][j] = acc0;
    }
  }
  __syncthreads();                    // zm = dvdx for C

  // ---- C: c = dvdx @ G -> out ----
  if (tid < SMP * 8) {
    int s = tid >> 3, a = tid & 7;
    float acc0 = 0.0f;
    #pragma unroll
    for (int j = 0; j < 32; ++j) acc0 = fmaf(zm[s][j], G[j * 8 + a], acc0);
    out[(size_t)(s0 + s) * 8 + a] = acc0;
  }
}

// ---------------- BoxCDQP: in-place on d_out (c -> u) ----------------
__global__ __launch_bounds__(256) void k_qp(float* __restrict__ out,
                                            const float* __restrict__ R,
                                            const float* __restrict__ lower,
                                            const float* __restrict__ upper) {
  int t = blockIdx.x * 256 + threadIdx.x;
  float q[8][8], u[8], cc[8], lo[8], hi[8], dg[8];
  #pragma unroll
  for (int i = 0; i < 8; ++i) {
    lo[i] = lower[i];
    hi[i] = upper[i];
    u[i] = 0.0f;
    cc[i] = out[(size_t)t * 8 + i];
    #pragma unroll
    for (int j = 0; j < 8; ++j) q[i][j] = 2.0f * R[i * 8 + j];
  }
  #pragma unroll
  for (int i = 0; i < 8; ++i) dg[i] = q[i][i];

  #pragma unroll 1
  for (int it = 0; it < 30; ++it) {
    #pragma unroll
    for (int i = 0; i < 8; ++i) {
      float g = cc[i];
      #pragma unroll
      for (int j = 0; j < 8; ++j) g = fmaf(q[i][j], u[j], g);
      float v = u[i] - g / dg[i];
      u[i] = fminf(fmaxf(v, lo[i]), hi[i]);
    }
  }
  #pragma unroll
  for (int i = 0; i < 8; ++i) out[(size_t)t * 8 + i] = u[i];
}

extern "C" void kernel_launch(void* const* d_in, const int* in_sizes, int n_in,
                              void* d_out, int out_size, void* d_ws, size_t ws_size,
                              hipStream_t stream) {
  const float* x    = (const float*)d_in[0];
  // d_in[1] = t (unused)
  const float* W0   = (const float*)d_in[2];
  const float* b0   = (const float*)d_in[3];
  const float* W1   = (const float*)d_in[4];
  const float* b1   = (const float*)d_in[5];
  const float* W2   = (const float*)d_in[6];
  const float* b2   = (const float*)d_in[7];
  const float* Wout = (const float*)d_in[8];
  const float* bout = (const float*)d_in[9];
  const float* G    = (const float*)d_in[10];
  const float* R    = (const float*)d_in[11];
  const float* lower= (const float*)d_in[12];
  const float* upper= (const float*)d_in[13];
  float* out = (float*)d_out;
  float* ws  = (float*)d_ws;

  const int B = in_sizes[0] / 32;   // 131072

  k_prep<<<256, 256, 0, stream>>>(W1, W2, Wout, ws);
  k_main<<<B / SMP, THREADS, 0, stream>>>(x, W0, b0, W1, b1, W2, b2,
                                          Wout, bout, G, ws, out);
  k_qp<<<B / 256, 256, 0, stream>>>(out, R, lower, upper);
}

// Round 7
// 2055.958 us; speedup vs baseline: 1.1549x; 1.0240x over previous
//
#include <hip/hip_runtime.h>
#include <math.h>

typedef float f4 __attribute__((ext_vector_type(4)));
typedef float f2 __attribute__((ext_vector_type(2)));

#define THREADS 256
#define HID 256
#define SMP 16   // samples per block (4 waves x 4 samples)

// ---------------- prep: transpose weights into ws ----------------
// ws layout (floats): [0]=W1T 256x256 (W1T[k][n]=W1[n][k]),
//   [65536]=W2T 256x256, [131072]=WoutT 32x256 (WoutT[j][k]=Wout[k][j])
__global__ void k_prep(const float* __restrict__ W1, const float* __restrict__ W2,
                       const float* __restrict__ Wout, float* __restrict__ ws) {
  float* W1T = ws;
  float* W2T = ws + 65536;
  float* WoutT = ws + 131072;
  int tid = blockIdx.x * 256 + threadIdx.x;
  if (tid < 65536) {
    int k = tid >> 8, n = tid & 255;
    W1T[tid] = W1[n * 256 + k];
    W2T[tid] = W2[n * 256 + k];
    if (tid < 8192) {
      int k2 = tid >> 8, n2 = tid & 255;   // WoutT[32][256]
      WoutT[tid] = Wout[n2 * 32 + k2];
    }
  }
}

// softplus = np fp32 semantics (DO NOT TOUCH — mask-critical):
//   sp = max(z,0) + log1pf(expf(-|z|)), each libm call correctly rounded
//   via double intermediates. Verified bit-faithful in rounds 6-8.
__device__ __forceinline__ float sp_cr(float z) {
  float az = fabsf(z);
  float e  = (float)exp(-(double)az);
  float lp = (float)log1p((double)e);
  return fmaxf(z, 0.0f) + lp;
}

// backward factor: sigmoid(z) = 1 - exp(-softplus(z)) from stored activation.
__device__ __forceinline__ float sig_from_h(float h) {
  return 1.0f - __expf(-h);
}

// ---------------- packed-fp32 MAC primitives (VOP3P) ----------------
// v_pk_* f32 = two independent IEEE fp32 ops (half-rate on gfx950 — no FLOP
// gain, but halves inst count / issue slots). Identical rounding to scalar.
// op_sel broadcasts one component of the h pair to both halves (no movs).

// d = (h[SEL] * w.lo, h[SEL] * w.hi)
template <int SEL>
__device__ __forceinline__ f2 pk_mul_b(f2 h, f2 w) {
  f2 d;
  if constexpr (SEL == 0)
    asm("v_pk_mul_f32 %0, %1, %2 op_sel:[0,0] op_sel_hi:[0,1]"
        : "=v"(d) : "v"(h), "v"(w));
  else
    asm("v_pk_mul_f32 %0, %1, %2 op_sel:[1,0] op_sel_hi:[1,1]"
        : "=v"(d) : "v"(h), "v"(w));
  return d;
}

__device__ __forceinline__ f2 pk_add(f2 a, f2 b) {
  f2 d;
  asm("v_pk_add_f32 %0, %1, %2" : "=v"(d) : "v"(a), "v"(b));
  return d;
}

// a += (h[SEL] * w.lo, h[SEL] * w.hi)   (fma rounding, bwd path)
template <int SEL>
__device__ __forceinline__ void pk_fma_b(f2& a, f2 h, f2 w) {
  if constexpr (SEL == 0)
    asm("v_pk_fma_f32 %0, %1, %2, %0 op_sel:[0,0,0] op_sel_hi:[0,1,1]"
        : "+v"(a) : "v"(h), "v"(w));
  else
    asm("v_pk_fma_f32 %0, %1, %2, %0 op_sel:[1,0,0] op_sel_hi:[1,1,1]"
        : "+v"(a) : "v"(h), "v"(w));
}

// 4 MACs (one k, one sample, 4 cols) using h component SEL of pair hp.
// FWD: mul-then-add separate rounding (np-exact); BWD: fmaf.
template <bool FWD, int SEL>
__device__ __forceinline__ void mac4(f2 (&a)[2], f2 hp, f4 wq) {
  f2 w01 = __builtin_shufflevector(wq, wq, 0, 1);
  f2 w23 = __builtin_shufflevector(wq, wq, 2, 3);
  if constexpr (FWD) {
    a[0] = pk_add(a[0], pk_mul_b<SEL>(hp, w01));
    a[1] = pk_add(a[1], pk_mul_b<SEL>(hp, w23));
  } else {
    pk_fma_b<SEL>(a[0], hp, w01);
    pk_fma_b<SEL>(a[1], hp, w23);
  }
}

// ---------------- forced async weight pipeline (asm) ----------------
// GLOAD4: issue 4 global_load_dwordx4 (k-rows g*4..g*4+3 of the panel) into
// a named register bank. volatile -> compiler cannot sink/merge them (R6's
// source-level dbuf was defeated: VGPR 68 showed the banks never lived).
// WAIT4: s_waitcnt vmcnt(4) carrying "+v" deps on the bank so consuming MACs
// cannot be scheduled above the wait (rule #18 via dataflow).
// Robustness: every WAIT4 has >=4 of OUR loads younger than the awaited bank,
// so the awaited bank is never among the 4 youngest — correct even if the
// compiler slips an unrelated VMEM op into the window.
#define GLOAD4(r0, r1, r2, r3, ptr)                                      \
  asm volatile("global_load_dwordx4 %0, %4, off\n\t"                     \
               "global_load_dwordx4 %1, %4, off offset:1024\n\t"         \
               "global_load_dwordx4 %2, %4, off offset:2048\n\t"         \
               "global_load_dwordx4 %3, %4, off offset:3072"             \
               : "=v"(r0), "=v"(r1), "=v"(r2), "=v"(r3)                  \
               : "v"(ptr))

#define WAIT4(r0, r1, r2, r3)                                            \
  asm volatile("s_waitcnt vmcnt(4)"                                      \
               : "+v"(r0), "+v"(r1), "+v"(r2), "+v"(r3))

#define WAIT0(r0, r1, r2, r3)                                            \
  asm volatile("s_waitcnt vmcnt(0)"                                      \
               : "+v"(r0), "+v"(r1), "+v"(r2), "+v"(r3))

// MAC one 4-k-row group (k = 4g..4g+3, ascending — np-exact order) for all
// 4 samples, weights from a named register bank.
template <int K, bool FWD>
__device__ __forceinline__ void mac_group(f2 (&acc)[4][2],
                                          const float* __restrict__ hin,
                                          int sA, int g, const f4& w0,
                                          const f4& w1, const f4& w2,
                                          const f4& w3) {
  #pragma unroll
  for (int s = 0; s < 4; ++s) {
    f4 hq = *(const f4*)&hin[(size_t)(sA + s) * K + g * 4];
    f2 h01 = __builtin_shufflevector(hq, hq, 0, 1);
    f2 h23 = __builtin_shufflevector(hq, hq, 2, 3);
    mac4<FWD, 0>(acc[s], h01, w0);   // k = 4g+0
    mac4<FWD, 1>(acc[s], h01, w1);   // k = 4g+1
    mac4<FWD, 0>(acc[s], h23, w2);   // k = 4g+2
    mac4<FWD, 1>(acc[s], h23, w3);   // k = 4g+3
  }
}

// ---------------- layer: weights streamed from L2, asm-pipelined ------------
// Two 4-row banks, 8 loads in flight, counted vmcnt(4) waits. Each bank's
// 64-pk MAC body (~256 cy) covers L2 latency (~200 cy). h rows via
// wave-uniform LDS broadcast. Summation order: ascending k, identical to
// R2/R5/R6 -> bit-identical output.
template <int K, bool FWD>
__device__ __forceinline__ void layer_g(const float* __restrict__ Wbase,
                                        const float* __restrict__ hin,
                                        int sA, int l, f2 (&acc)[4][2]) {
  #pragma unroll
  for (int s = 0; s < 4; ++s) {
    acc[s][0] = (f2){0.f, 0.f};
    acc[s][1] = (f2){0.f, 0.f};
  }
  const float* wp = Wbase + l * 4;
  constexpr int NG = K / 4;            // 4-row groups (8 or 64)
  f4 a0, a1, a2, a3, b0, b1, b2, b3;
  GLOAD4(a0, a1, a2, a3, wp);
  GLOAD4(b0, b1, b2, b3, wp + 1024);
  #pragma unroll 1
  for (int g = 0; g <= NG - 4; g += 2) {
    WAIT4(a0, a1, a2, a3);
    mac_group<K, FWD>(acc, hin, sA, g, a0, a1, a2, a3);
    GLOAD4(a0, a1, a2, a3, wp + (size_t)(g + 2) * 1024);
    WAIT4(b0, b1, b2, b3);
    mac_group<K, FWD>(acc, hin, sA, g + 1, b0, b1, b2, b3);
    GLOAD4(b0, b1, b2, b3, wp + (size_t)(g + 3) * 1024);
  }
  // epilogue: banks A(NG-2), B(NG-1) in flight
  WAIT4(a0, a1, a2, a3);
  mac_group<K, FWD>(acc, hin, sA, NG - 2, a0, a1, a2, a3);
  WAIT0(b0, b1, b2, b3);
  mac_group<K, FWD>(acc, hin, sA, NG - 1, b0, b1, b2, b3);
}

// softplus(acc + b) -> LDS row (scalar adds, same order/rounding as before)
__device__ __forceinline__ void sp_store(const f2 (&a)[2],
                                         const float* __restrict__ b,
                                         float* __restrict__ dstrow, int l) {
  f4 bv = *(const f4*)&b[l * 4];
  f4 o;
  o[0] = sp_cr(a[0][0] + bv[0]);
  o[1] = sp_cr(a[0][1] + bv[1]);
  o[2] = sp_cr(a[1][0] + bv[2]);
  o[3] = sp_cr(a[1][1] + bv[3]);
  *(f4*)&dstrow[l * 4] = o;
}

// dz = acc * sig(h) -> LDS row in-place
__device__ __forceinline__ void sig_store(const f2 (&a)[2],
                                          float* __restrict__ hrow, int l) {
  f4 h = *(f4*)&hrow[l * 4];
  f4 d;
  d[0] = a[0][0] * sig_from_h(h[0]);
  d[1] = a[0][1] * sig_from_h(h[1]);
  d[2] = a[1][0] * sig_from_h(h[2]);
  d[3] = a[1][1] * sig_from_h(h[3]);
  *(f4*)&hrow[l * 4] = d;
}

// ---------------- fused MLP fwd (np-faithful) + bwd + c = dvdx@G ------------
// R15 = R6 structure (packed MACs, L2-streamed weights, barrier-light,
// 3 blocks/CU) with the weight prefetch FORCED via asm loads + counted
// vmcnt(4) (R6's source-level dbuf was compiler-defeated — VGPR 68).
// Output must be bit-identical (absmax 0.0004882812) — regression check.
__global__ __launch_bounds__(THREADS, 3) void k_main(
    const float* __restrict__ x,
    const float* __restrict__ W0, const float* __restrict__ b0,
    const float* __restrict__ W1, const float* __restrict__ b1,
    const float* __restrict__ W2, const float* __restrict__ b2,
    const float* __restrict__ Wout, const float* __restrict__ bout,
    const float* __restrict__ G, const float* __restrict__ ws,
    float* __restrict__ out) {
  __shared__ float xs[SMP][32];       // 2 KB
  __shared__ float ha[SMP][HID];      // 16 KB : h0, then dz0
  __shared__ float hb[SMP][HID];      // 16 KB : h1, then dz1
  __shared__ float hc[SMP][HID];      // 16 KB : h2, then dz2
  __shared__ float zm[SMP][32];       // 2 KB  : mask, then dvdx

  const float* W1T = ws;
  const float* W2T = ws + 65536;
  const float* WoutT = ws + 131072;

  const int tid = threadIdx.x;
  const int w = tid >> 6;             // wave 0..3 -> samples w*4 .. w*4+3
  const int l = tid & 63;             // cols l*4..l*4+3
  const int sA = w * 4;
  const int s0 = blockIdx.x * SMP;

  for (int i = tid; i < SMP * 32; i += THREADS) {
    xs[i >> 5][i & 31] = x[(size_t)s0 * 32 + i];
  }
  __syncthreads();                    // xs visible

  f2 acc[4][2];

  // ---- L0: h0 = softplus(xs @ W0 + b0) -> ha  (K=32) ----
  layer_g<32, true>(W0, &xs[0][0], sA, l, acc);
  sp_store(acc[0], b0, &ha[sA + 0][0], l);
  sp_store(acc[1], b0, &ha[sA + 1][0], l);
  sp_store(acc[2], b0, &ha[sA + 2][0], l);
  sp_store(acc[3], b0, &ha[sA + 3][0], l);
  // own-wave rows only -> no barrier (same-wave LDS RAW ordered by lgkmcnt)

  // ---- L1: h1 = softplus(h0 @ W1 + b1) -> hb  (K=256) ----
  layer_g<256, true>(W1, &ha[0][0], sA, l, acc);
  sp_store(acc[0], b1, &hb[sA + 0][0], l);
  sp_store(acc[1], b1, &hb[sA + 1][0], l);
  sp_store(acc[2], b1, &hb[sA + 2][0], l);
  sp_store(acc[3], b1, &hb[sA + 3][0], l);

  // ---- L2: h2 = softplus(h1 @ W2 + b2) -> hc ----
  layer_g<256, true>(W2, &hb[0][0], sA, l, acc);
  sp_store(acc[0], b2, &hc[sA + 0][0], l);
  sp_store(acc[1], b2, &hc[sA + 1][0], l);
  sp_store(acc[2], b2, &hc[sA + 2][0], l);
  sp_store(acc[3], b2, &hc[sA + 3][0], l);
  __syncthreads();                    // hc all rows for L3 (cross-wave)

  // ---- L3: z3 = h2 @ Wout + bout ; mask -> zm (exact np order; WoutT rows,
  // ---- cache-resident). 512 (s,j) pairs -> 2 reps. ----
  {
#pragma clang fp contract(off)
    #pragma unroll
    for (int rep = 0; rep < 2; ++rep) {
      int idx = tid + rep * THREADS;
      int s = idx >> 5, j = idx & 31;
      const float* wrow = WoutT + (size_t)j * 256;   // WoutT[j][k] = Wout[k][j]
      float acc0 = 0.0f;
      #pragma unroll 4
      for (int k = 0; k < 256; k += 4) {
        f4 hv = *(const f4*)&hc[s][k];
        f4 wv = *(const f4*)&wrow[k];
        #pragma unroll
        for (int kk = 0; kk < 4; ++kk) {
          float p = hv[kk] * wv[kk];
          acc0 = acc0 + p;
        }
      }
      zm[s][j] = (acc0 + bout[j] > 0.0f) ? 1.0f : 0.0f;
    }
  }
  __syncthreads();                    // zm visible to B2 (cross-wave rows)

  // ---- B2: dz2 = (mask @ WoutT) * sig(h2) -> hc in-place (K=32) ----
  layer_g<32, false>(WoutT, &zm[0][0], sA, l, acc);
  sig_store(acc[0], &hc[sA + 0][0], l);
  sig_store(acc[1], &hc[sA + 1][0], l);
  sig_store(acc[2], &hc[sA + 2][0], l);
  sig_store(acc[3], &hc[sA + 3][0], l);

  // ---- B1: dz1 = (dz2 @ W2T) * sig(h1) -> hb in-place ----
  layer_g<256, false>(W2T, &hc[0][0], sA, l, acc);
  sig_store(acc[0], &hb[sA + 0][0], l);
  sig_store(acc[1], &hb[sA + 1][0], l);
  sig_store(acc[2], &hb[sA + 2][0], l);
  sig_store(acc[3], &hb[sA + 3][0], l);

  // ---- B0: dz0 = (dz1 @ W1T) * sig(h0) -> ha in-place ----
  layer_g<256, false>(W1T, &hb[0][0], sA, l, acc);
  sig_store(acc[0], &ha[sA + 0][0], l);
  sig_store(acc[1], &ha[sA + 1][0], l);
  sig_store(acc[2], &ha[sA + 2][0], l);
  sig_store(acc[3], &ha[sA + 3][0], l);
  __syncthreads();                    // ha = dz0 all rows for BX (cross-wave)

  // ---- BX: dvdx = dz0 @ W0T -> zm (W0 rows, cache-resident) ----
  {
    #pragma unroll
    for (int rep = 0; rep < 2; ++rep) {
      int idx = tid + rep * THREADS;
      int s = idx >> 5, j = idx & 31;
      const float* wrow = W0 + (size_t)j * 256;      // W0[j][k]
      float acc0 = 0.0f;
      #pragma unroll 4
      for (int k = 0; k < 256; k += 4) {
        f4 hv = *(const f4*)&ha[s][k];
        f4 wv = *(const f4*)&wrow[k];
        #pragma unroll
        for (int kk = 0; kk < 4; ++kk) {
          acc0 = fmaf(hv[kk], wv[kk], acc0);
        }
      }
      zm[s][j] = acc0;
    }
  }
  __syncthreads();                    // zm = dvdx for C

  // ---- C: c = dvdx @ G -> out ----
  if (tid < SMP * 8) {
    int s = tid >> 3, a = tid & 7;
    float acc0 = 0.0f;
    #pragma unroll
    for (int j = 0; j < 32; ++j) acc0 = fmaf(zm[s][j], G[j * 8 + a], acc0);
    out[(size_t)(s0 + s) * 8 + a] = acc0;
  }
}

// ---------------- BoxCDQP: in-place on d_out (c -> u) ----------------
__global__ __launch_bounds__(256) void k_qp(float* __restrict__ out,
                                            const float* __restrict__ R,
                                            const float* __restrict__ lower,
                                            const float* __restrict__ upper) {
  int t = blockIdx.x * 256 + threadIdx.x;
  float q[8][8], u[8], cc[8], lo[8], hi[8], dg[8];
  #pragma unroll
  for (int i = 0; i < 8; ++i) {
    lo[i] = lower[i];
    hi[i] = upper[i];
    u[i] = 0.0f;
    cc[i] = out[(size_t)t * 8 + i];
    #pragma unroll
    for (int j = 0; j < 8; ++j) q[i][j] = 2.0f * R[i * 8 + j];
  }
  #pragma unroll
  for (int i = 0; i < 8; ++i) dg[i] = q[i][i];

  #pragma unroll 1
  for (int it = 0; it < 30; ++it) {
    #pragma unroll
    for (int i = 0; i < 8; ++i) {
      float g = cc[i];
      #pragma unroll
      for (int j = 0; j < 8; ++j) g = fmaf(q[i][j], u[j], g);
      float v = u[i] - g / dg[i];
      u[i] = fminf(fmaxf(v, lo[i]), hi[i]);
    }
  }
  #pragma unroll
  for (int i = 0; i < 8; ++i) out[(size_t)t * 8 + i] = u[i];
}

extern "C" void kernel_launch(void* const* d_in, const int* in_sizes, int n_in,
                              void* d_out, int out_size, void* d_ws, size_t ws_size,
                              hipStream_t stream) {
  const float* x    = (const float*)d_in[0];
  // d_in[1] = t (unused)
  const float* W0   = (const float*)d_in[2];
  const float* b0   = (const float*)d_in[3];
  const float* W1   = (const float*)d_in[4];
  const float* b1   = (const float*)d_in[5];
  const float* W2   = (const float*)d_in[6];
  const float* b2   = (const float*)d_in[7];
  const float* Wout = (const float*)d_in[8];
  const float* bout = (const float*)d_in[9];
  const float* G    = (const float*)d_in[10];
  const float* R    = (const float*)d_in[11];
  const float* lower= (const float*)d_in[12];
  const float* upper= (const float*)d_in[13];
  float* out = (float*)d_out;
  float* ws  = (float*)d_ws;

  const int B = in_sizes[0] / 32;   // 131072

  k_prep<<<256, 256, 0, stream>>>(W1, W2, Wout, ws);
  k_main<<<B / SMP, THREADS, 0, stream>>>(x, W0, b0, W1, b1, W2, b2,
                                          Wout, bout, G, ws, out);
  k_qp<<<B / 256, 256, 0, stream>>>(out, R, lower, upper);
}